// Round 8
// baseline (64.960 us; speedup 1.0000x reference)
//
#include <hip/hip_runtime.h>
#include <hip/hip_bf16.h>

typedef __bf16 bf16_t;
typedef __bf16 bf16x8 __attribute__((ext_vector_type(8)));
typedef __bf16 bf16x4 __attribute__((ext_vector_type(4)));
typedef float  f32x4  __attribute__((ext_vector_type(4)));

#define MFMA_BF16(A, B, C) __builtin_amdgcn_mfma_f32_16x16x32_bf16((A), (B), (C), 0, 0, 0)

#define BATCH 8
#define SEQ   2048
#define EMB   1024
#define HEAD  64

typedef __attribute__((address_space(3))) void as3_void;
typedef const __attribute__((address_space(1))) void as1_void;
#define GLOAD_LDS16(g, l) \
  __builtin_amdgcn_global_load_lds((as1_void*)(g), (as3_void*)(l), 16, 0, 0)

// ---------------------------------------------------------------------------
// Kernel 0: W [1024][64] fp32 x3 -> WT bf16 [192][1024] (transposed).
// Wq gets scale log2(e)/32 folded in (attn uses exp2 -> saves a mul/elem).
// ---------------------------------------------------------------------------
__global__ __launch_bounds__(256) void wtrans_kernel(
    const float* __restrict__ Wq, const float* __restrict__ Wk,
    const float* __restrict__ Wv, bf16_t* __restrict__ WT)
{
  __shared__ float tile[64][65];
  const int m  = blockIdx.x >> 4;
  const int kt = blockIdx.x & 15;
  const float* W = (m == 0) ? Wq : (m == 1) ? Wk : Wv;
  const float scale = (m == 0) ? 0.045084219f : 1.0f;   // log2(e)/32
  const int k0 = kt * 64;

  #pragma unroll
  for (int i = 0; i < 16; ++i) {
    int idx = i * 256 + threadIdx.x;
    int kk = idx >> 6, n = idx & 63;
    tile[kk][n] = W[(size_t)(k0 + kk) * HEAD + n];
  }
  __syncthreads();
  #pragma unroll
  for (int i = 0; i < 16; ++i) {
    int idx = i * 256 + threadIdx.x;
    int n = idx >> 6, kk = idx & 63;
    WT[((size_t)m * HEAD + n) * EMB + k0 + kk] = (bf16_t)(tile[kk][n] * scale);
  }
}

// ---------------------------------------------------------------------------
// Kernel 1: qkv v8 — v7's ring-4 counted-vmcnt pipeline, but BM=32 and
// grid 512 -> 2 INDEPENDENT blocks per CU (the missing TLP: one block's
// stage/wait overlaps the other's compute; m114 wave-level overlap).
// 4 waves = 4-way N-split, wave = 32 rows x 48 cols, full K (no reduction).
// Ring 4 x 16KB bufs (64KB -> exactly 2 blocks/CU). 4 glds/wave/step
// (1 A + 3 B) -> steady vmcnt(8) (2 steps of slack), never 0 in loop.
// Swizzle: A (fp32, 128B rows) byte^=(row&7)<<4 both sides; B (64B rows)
// needs none (verified <=2-way).
// ---------------------------------------------------------------------------
#define A_BYTES 4096      // 32 rows x 128 B (fp32 k-slice of 32)
#define B_BYTES 12288     // 192 rows x 64 B (bf16 k-slice of 32)
#define BUF_BYTES 16384

__global__ __launch_bounds__(256, 2) void qkv_kernel(
    const float* __restrict__ x, const bf16_t* __restrict__ WT,
    bf16_t* __restrict__ qo, bf16_t* __restrict__ ko, bf16_t* __restrict__ vT)
{
  __shared__ char lds[4 * BUF_BYTES];

  const int tid  = threadIdx.x;
  const int lane = tid & 63;
  const int wave = tid >> 6;
  const int l15 = lane & 15, l4 = lane >> 4;
  const int rowbase = blockIdx.x * 32;

  // A DMA: 1 instr/wave (g=wave) covers rows 8g..8g+7; lane -> row 8g+(l>>3),
  // dest byte (l&7)*16 in 128B row; source col pre-XORed with the read swizzle.
  const int a_row_sub = lane >> 3;
  const int a_src_off = (((lane & 7) ^ a_row_sub) << 4);
  // B DMA: 3 instr/wave (g=wave*3+j) cover rows 16g..16g+15; lane -> row
  // 16g+(l>>2), byte (l&3)*16 in 64B row; no swizzle needed.
  const int b_row_sub = lane >> 2;
  const int b_src_off = (lane & 3) * 16;

  const int aswz = (l15 & 7) << 4;     // read-side XOR (row&7 == l15&7)

  f32x4 acc[2][3];
  #pragma unroll
  for (int m = 0; m < 2; ++m)
    #pragma unroll
    for (int n = 0; n < 3; ++n) acc[m][n] = (f32x4){0.f, 0.f, 0.f, 0.f};

#define STAGE(t)                                                               \
  {                                                                            \
    char* buf = lds + ((t) & 3) * BUF_BYTES;                                   \
    {                                                                          \
      const int row = 8 * wave + a_row_sub;                                    \
      const char* src = (const char*)x + (size_t)(rowbase + row) * 4096        \
                        + (size_t)(t) * 128 + a_src_off;                       \
      GLOAD_LDS16(src, buf + wave * 1024);                                     \
    }                                                                          \
    _Pragma("unroll")                                                          \
    for (int j = 0; j < 3; ++j) {                                              \
      const int g = wave * 3 + j;                                              \
      const int row = 16 * g + b_row_sub;                                      \
      const char* src = (const char*)WT + (size_t)row * 2048                   \
                        + (size_t)(t) * 64 + b_src_off;                        \
      GLOAD_LDS16(src, buf + A_BYTES + g * 1024);                              \
    }                                                                          \
  }

#define COMPUTE(t)                                                             \
  {                                                                            \
    const char* Ab = lds + ((t) & 3) * BUF_BYTES;                              \
    const char* Bb = Ab + A_BYTES;                                             \
    bf16x8 afr[2];                                                             \
    _Pragma("unroll")                                                          \
    for (int m = 0; m < 2; ++m) {                                              \
      const int R = m * 16 + l15;                                              \
      f32x4 p0 = *(const f32x4*)(Ab + R * 128 + ((l4 * 32) ^ aswz));           \
      f32x4 p1 = *(const f32x4*)(Ab + R * 128 + ((l4 * 32 + 16) ^ aswz));      \
      bf16x8 a;                                                                \
      a[0] = (bf16_t)p0.x; a[1] = (bf16_t)p0.y;                                \
      a[2] = (bf16_t)p0.z; a[3] = (bf16_t)p0.w;                                \
      a[4] = (bf16_t)p1.x; a[5] = (bf16_t)p1.y;                                \
      a[6] = (bf16_t)p1.z; a[7] = (bf16_t)p1.w;                                \
      afr[m] = a;                                                              \
    }                                                                          \
    _Pragma("unroll")                                                          \
    for (int n = 0; n < 3; ++n) {                                              \
      const int R = wave * 48 + n * 16 + l15;                                  \
      bf16x8 b = *(const bf16x8*)(Bb + R * 64 + l4 * 16);                      \
      acc[0][n] = MFMA_BF16(afr[0], b, acc[0][n]);                             \
      acc[1][n] = MFMA_BF16(afr[1], b, acc[1][n]);                             \
    }                                                                          \
  }

  // prologue: 3 steps in flight (12 outstanding); wait step 0 (vmcnt 8)
  STAGE(0); STAGE(1); STAGE(2);
  asm volatile("s_waitcnt vmcnt(8)" ::: "memory");
  __builtin_amdgcn_s_barrier();

  #pragma unroll 4
  for (int t = 0; t < 29; ++t) {
    COMPUTE(t);
    STAGE(t + 3);
    asm volatile("s_waitcnt vmcnt(8)" ::: "memory");  // step t+1 landed
    __builtin_amdgcn_s_barrier();
  }
  COMPUTE(29);
  asm volatile("s_waitcnt vmcnt(4)" ::: "memory");
  __builtin_amdgcn_s_barrier();
  COMPUTE(30);
  asm volatile("s_waitcnt vmcnt(0)" ::: "memory");
  __builtin_amdgcn_s_barrier();
  COMPUTE(31);
#undef STAGE
#undef COMPUTE

  // epilogue: D row = l4*4+i, col = wave*48 + n*16 + l15 (m89-verified)
  #pragma unroll
  for (int n = 0; n < 3; ++n) {
    const int col = wave * 48 + n * 16;               // wave-uniform base
    #pragma unroll
    for (int m = 0; m < 2; ++m) {
      const int r0 = rowbase + m * 16 + l4 * 4;
      if (col < 64) {
        #pragma unroll
        for (int i = 0; i < 4; ++i)
          qo[(size_t)(r0 + i) * HEAD + col + l15] = (bf16_t)acc[m][n][i];
      } else if (col < 128) {
        #pragma unroll
        for (int i = 0; i < 4; ++i)
          ko[(size_t)(r0 + i) * HEAD + col - 64 + l15] = (bf16_t)acc[m][n][i];
      } else {
        const int h = col - 128 + l15;
        bf16x4 pk;
        #pragma unroll
        for (int i = 0; i < 4; ++i) pk[i] = (bf16_t)acc[m][n][i];
        *(bf16x4*)(vT + ((size_t)(r0 >> 11) * HEAD + h) * SEQ + (r0 & 2047)) = pk;
      }
    }
  }
}

// ---------------------------------------------------------------------------
// Kernel 2: attn v5 — BALANCED pair-block. Block = strips (p, 127-p);
// the two strips' tile lists are concatenated (33-34 tiles, near-constant)
// and dealt round-robin to ALL 8 waves (wave w: indices w, w+8, ...).
// Each wave carries both strips' accumulators; two-pass LDS reduce.
// launch_bounds(512,2): LDS caps at 2 blocks/CU anyway, so allow 128 VGPR
// (the old (512,4) forced <=64 VGPR -> spills). exp2f (scale pre-folded).
// ---------------------------------------------------------------------------
__global__ __launch_bounds__(512, 2) void attn_kernel(
    const bf16_t* __restrict__ q, const bf16_t* __restrict__ k,
    const bf16_t* __restrict__ vT, float* __restrict__ out)
{
  __shared__ bf16_t P[8][16][72];
  __shared__ float olds[8][16][68];
  __shared__ float lsums[8][16];
  const int lane = threadIdx.x & 63;
  const int wave = threadIdx.x >> 6;
  const int l15 = lane & 15, l4 = lane >> 4;
  const int batch = blockIdx.x & 7;        // bid%8 -> one batch per XCD
  const int pair  = blockIdx.x >> 3;       // 0..63
  const int stripA = pair, stripB = 127 - pair;
  const int nA = (stripA >> 2) + 1;        // k-tiles for strip A
  const int nB = (stripB >> 2) + 1;
  const int ntot = nA + nB;                // 33 or 34

  const bf16_t* kb = k  + (size_t)batch * SEQ * HEAD;
  const bf16_t* vb = vT + (size_t)batch * HEAD * SEQ;
  const bf16_t* qbA = q + ((size_t)batch * SEQ + stripA * 16) * HEAD;
  const bf16_t* qbB = q + ((size_t)batch * SEQ + stripB * 16) * HEAD;

  const bf16x8 aqA0 = *(const bf16x8*)(qbA + (size_t)l15 * HEAD + l4 * 8);
  const bf16x8 aqA1 = *(const bf16x8*)(qbA + (size_t)l15 * HEAD + 32 + l4 * 8);
  const bf16x8 aqB0 = *(const bf16x8*)(qbB + (size_t)l15 * HEAD + l4 * 8);
  const bf16x8 aqB1 = *(const bf16x8*)(qbB + (size_t)l15 * HEAD + 32 + l4 * 8);

  f32x4 oA[4], oB[4];
  #pragma unroll
  for (int i = 0; i < 4; ++i) {
    oA[i] = (f32x4){0.f, 0.f, 0.f, 0.f};
    oB[i] = (f32x4){0.f, 0.f, 0.f, 0.f};
  }
  float lsA[4] = {0.f, 0.f, 0.f, 0.f};
  float lsB[4] = {0.f, 0.f, 0.f, 0.f};

  for (int i = wave; i < ntot; i += 8) {   // wave-uniform trip count & branch
    const bool isA = (i < nA);
    const int tile = isA ? i : (i - nA);
    const int nS   = isA ? nA : nB;
    const int qrow = (isA ? stripA : stripB) * 16;
    const int kv0  = tile * 64;
    const bf16x8 aq0 = isA ? aqA0 : aqB0;
    const bf16x8 aq1 = isA ? aqA1 : aqB1;

    // --- S = Q K^T ---
    f32x4 s[4];
    #pragma unroll
    for (int nf = 0; nf < 4; ++nf) s[nf] = (f32x4){0.f, 0.f, 0.f, 0.f};
    __builtin_amdgcn_s_setprio(1);
    #pragma unroll
    for (int nf = 0; nf < 4; ++nf) {
      const bf16_t* kp = kb + (size_t)(kv0 + nf * 16 + l15) * HEAD + l4 * 8;
      bf16x8 b0 = *(const bf16x8*)kp;
      bf16x8 b1 = *(const bf16x8*)(kp + 32);
      s[nf] = MFMA_BF16(aq0, b0, s[nf]);
      s[nf] = MFMA_BF16(aq1, b1, s[nf]);
    }
    __builtin_amdgcn_s_setprio(0);

    // --- P = exp2(S) (log2e folded into Wq), causal mask on diag tile ---
    const bool diag = (tile == nS - 1);
    float tsum[4] = {0.f, 0.f, 0.f, 0.f};
    #pragma unroll
    for (int nf = 0; nf < 4; ++nf) {
      #pragma unroll
      for (int i2 = 0; i2 < 4; ++i2) {
        float e = exp2f(s[nf][i2]);
        if (diag) {
          const int col = kv0 + nf * 16 + l15;
          const int row = qrow + l4 * 4 + i2;
          e = (col <= row) ? e : 0.f;
        }
        tsum[i2] += e;
        P[wave][l4 * 4 + i2][nf * 16 + l15] = (bf16_t)e;
      }
    }

    // V loads issued here (consumed after the lgkm wait -> latency overlaps)
    bf16x8 v0[4], v1[4];
    #pragma unroll
    for (int nf = 0; nf < 4; ++nf) {
      const bf16_t* vp = vb + (size_t)(nf * 16 + l15) * SEQ + kv0 + l4 * 8;
      v0[nf] = *(const bf16x8*)vp;
      v1[nf] = *(const bf16x8*)(vp + 32);
    }
    asm volatile("s_waitcnt lgkmcnt(0)" ::: "memory");   // per-wave P visible

    bf16x8 ap0 = *(const bf16x8*)&P[wave][l15][l4 * 8];
    bf16x8 ap1 = *(const bf16x8*)&P[wave][l15][32 + l4 * 8];
    __builtin_amdgcn_s_setprio(1);
    if (isA) {
      #pragma unroll
      for (int nf = 0; nf < 4; ++nf) {
        oA[nf] = MFMA_BF16(ap0, v0[nf], oA[nf]);
        oA[nf] = MFMA_BF16(ap1, v1[nf], oA[nf]);
      }
      #pragma unroll
      for (int i2 = 0; i2 < 4; ++i2) lsA[i2] += tsum[i2];
    } else {
      #pragma unroll
      for (int nf = 0; nf < 4; ++nf) {
        oB[nf] = MFMA_BF16(ap0, v0[nf], oB[nf]);
        oB[nf] = MFMA_BF16(ap1, v1[nf], oB[nf]);
      }
      #pragma unroll
      for (int i2 = 0; i2 < 4; ++i2) lsB[i2] += tsum[i2];
    }
    __builtin_amdgcn_s_setprio(0);
  }

  // ---- two-pass reduce (same LDS reused; barrier-separated) ----
  #pragma unroll
  for (int pass = 0; pass < 2; ++pass) {
    // publish this pass's partials
    #pragma unroll
    for (int i = 0; i < 4; ++i) {
      float v = pass == 0 ? lsA[i] : lsB[i];
      v += __shfl_xor(v, 1);
      v += __shfl_xor(v, 2);
      v += __shfl_xor(v, 4);
      v += __shfl_xor(v, 8);
      if (l15 == 0) lsums[wave][l4 * 4 + i] = v;
    }
    #pragma unroll
    for (int nf = 0; nf < 4; ++nf)
      #pragma unroll
      for (int i = 0; i < 4; ++i)
        olds[wave][l4 * 4 + i][nf * 16 + l15] = pass == 0 ? oA[nf][i] : oB[nf][i];
    __syncthreads();

    if (threadIdx.x < 256) {
      const int r = threadIdx.x >> 4, c0 = threadIdx.x & 15;
      float sum = 0.f;
      #pragma unroll
      for (int w = 0; w < 8; ++w) sum += lsums[w][r];
      const float rinv = 1.0f / sum;
      const int strip = pass == 0 ? stripA : stripB;
      float* ob = out + ((size_t)batch * SEQ + strip * 16 + r) * HEAD;
      #pragma unroll
      for (int j = 0; j < 4; ++j) {
        const int c = c0 + 16 * j;
        float v = 0.f;
        #pragma unroll
        for (int w = 0; w < 8; ++w) v += olds[w][r][c];
        ob[c] = v * rinv;
      }
    }
    __syncthreads();
  }
}

// ---------------------------------------------------------------------------
extern "C" void kernel_launch(void* const* d_in, const int* in_sizes, int n_in,
                              void* d_out, int out_size, void* d_ws, size_t ws_size,
                              hipStream_t stream)
{
  const float* x  = (const float*)d_in[0];
  const float* Wq = (const float*)d_in[1];
  const float* Wk = (const float*)d_in[2];
  const float* Wv = (const float*)d_in[3];
  float* out = (float*)d_out;

  const size_t SZ_QKV = (size_t)BATCH * SEQ * HEAD * sizeof(bf16_t);   // 2 MiB
  if (ws_size < 3 * SZ_QKV + (size_t)192 * EMB * sizeof(bf16_t)) return;
  char* ws = (char*)d_ws;
  bf16_t* qo = (bf16_t*)(ws);
  bf16_t* ko = (bf16_t*)(ws + SZ_QKV);
  bf16_t* vT = (bf16_t*)(ws + 2 * SZ_QKV);
  bf16_t* WT = (bf16_t*)(ws + 3 * SZ_QKV);

  wtrans_kernel<<<dim3(48),  dim3(256), 0, stream>>>(Wq, Wk, Wv, WT);
  qkv_kernel  <<<dim3(512), dim3(256), 0, stream>>>(x, WT, qo, ko, vT);
  attn_kernel <<<dim3(512), dim3(512), 0, stream>>>(qo, ko, vT, out);
}

// Round 9
// 59.620 us; speedup vs baseline: 1.0896x; 1.0896x over previous
//
#include <hip/hip_runtime.h>
#include <hip/hip_bf16.h>

typedef __bf16 bf16_t;
typedef __bf16 bf16x8 __attribute__((ext_vector_type(8)));
typedef __bf16 bf16x4 __attribute__((ext_vector_type(4)));
typedef float  f32x4  __attribute__((ext_vector_type(4)));

#define MFMA_BF16(A, B, C) __builtin_amdgcn_mfma_f32_16x16x32_bf16((A), (B), (C), 0, 0, 0)

#define BATCH 8
#define SEQ   2048
#define EMB   1024
#define HEAD  64

typedef __attribute__((address_space(3))) void as3_void;
typedef const __attribute__((address_space(1))) void as1_void;
#define GLOAD_LDS16(g, l) \
  __builtin_amdgcn_global_load_lds((as1_void*)(g), (as3_void*)(l), 16, 0, 0)

// ---------------------------------------------------------------------------
// Kernel 0: W [1024][64] fp32 x3 -> WT bf16 [192][1024] (transposed).
// Wq gets scale log2(e)/32 folded in (attn uses exp2).
// ---------------------------------------------------------------------------
__global__ __launch_bounds__(256) void wtrans_kernel(
    const float* __restrict__ Wq, const float* __restrict__ Wk,
    const float* __restrict__ Wv, bf16_t* __restrict__ WT)
{
  __shared__ float tile[64][65];
  const int m  = blockIdx.x >> 4;
  const int kt = blockIdx.x & 15;
  const float* W = (m == 0) ? Wq : (m == 1) ? Wk : Wv;
  const float scale = (m == 0) ? 0.045084219f : 1.0f;   // log2(e)/32
  const int k0 = kt * 64;

  #pragma unroll
  for (int i = 0; i < 16; ++i) {
    int idx = i * 256 + threadIdx.x;
    int kk = idx >> 6, n = idx & 63;
    tile[kk][n] = W[(size_t)(k0 + kk) * HEAD + n];
  }
  __syncthreads();
  #pragma unroll
  for (int i = 0; i < 16; ++i) {
    int idx = i * 256 + threadIdx.x;
    int n = idx >> 6, kk = idx & 63;
    WT[((size_t)m * HEAD + n) * EMB + k0 + kk] = (bf16_t)(tile[kk][n] * scale);
  }
}

// ---------------------------------------------------------------------------
// Kernel 1: qkv v9 — BM=64 x N=192 x BK=64, 256 blocks (1/CU), 8 waves
// (2m x 4n, wave = 32 rows x 48 cols, full K, no reduction).
// Ring-4 x 40KB bufs (160KB LDS), counted vmcnt(10) (2-step slack), raw
// s_barrier. 5 glds/wave/step (2 A + 3 B). Fixes vs v8:
//  * B reads were 8-WAY bank-conflicted since v7 -> B now XOR-swizzled
//    ((R&7)<<4 on 128B rows), A swizzled ((R&7)<<5 on 256B rows); both
//    pre-applied to the glds SOURCE (rule #21), reads 2-way = free.
//  * k-phase STAGGER per block ((bid>>3)&15): concurrent blocks read
//    DIFFERENT WT k-slices -> no same-address L2 line hotspot.
//  * staging volume back to 20KB/CU/step (B-total 98MB, not 196).
// ---------------------------------------------------------------------------
#define A_BYTES 16384     // 64 rows x 256 B (fp32, BK=64)
#define B_BYTES 24576     // 192 rows x 128 B (bf16, BK=64)
#define BUF_BYTES 40960

__global__ __launch_bounds__(512, 1) void qkv_kernel(
    const float* __restrict__ x, const bf16_t* __restrict__ WT,
    bf16_t* __restrict__ qo, bf16_t* __restrict__ ko, bf16_t* __restrict__ vT)
{
  __shared__ char lds[4 * BUF_BYTES];            // 160 KB

  const int tid  = threadIdx.x;
  const int lane = tid & 63;
  const int wave = tid >> 6;                     // 0..7
  const int l15 = lane & 15, l4 = lane >> 4;
  const int wm = wave >> 2, wn = wave & 3;
  const int rowbase = blockIdx.x * 64;
  const int phase = (blockIdx.x >> 3) & 15;      // k-stagger (sum order-free)

  // A DMA: instr g covers rows 4g..4g+3; lane -> row 4g+(l>>4), dest byte
  // (l&15)*16 in 256B row. Source pre-XORed with read swizzle (row&7)<<5,
  // row&7 = ((g&1)<<2)|(l>>4).
  const int a_rsub = lane >> 4;
  // B DMA: instr g covers rows 8g..8g+7; lane -> row 8g+(l>>3), dest byte
  // (l&7)*16 in 128B row. Source pre-XORed with (row&7)<<4, row&7 = l>>3.
  const int b_rsub = lane >> 3;
  const int b_koff = ((lane & 7) * 16) ^ (b_rsub << 4);

  const int aswz = (l15 & 7) << 5;               // read-side XORs (row&7==l15&7)
  const int bswz = (l15 & 7) << 4;

  f32x4 acc[2][3];
  #pragma unroll
  for (int m = 0; m < 2; ++m)
    #pragma unroll
    for (int n = 0; n < 3; ++n) acc[m][n] = (f32x4){0.f, 0.f, 0.f, 0.f};

#define STAGE(t)                                                               \
  {                                                                            \
    char* buf = lds + ((t) & 3) * BUF_BYTES;                                   \
    const int tp = ((t) + phase) & 15;                                         \
    _Pragma("unroll")                                                          \
    for (int j = 0; j < 2; ++j) {                                              \
      const int g = 2 * wave + j;                                              \
      const int koff = (l15 * 16) ^ ((((j) << 2) | a_rsub) << 5);              \
      const char* src = (const char*)x + (size_t)(rowbase + 4 * g + a_rsub)    \
                        * 4096 + (size_t)tp * 256 + koff;                      \
      GLOAD_LDS16(src, buf + g * 1024);                                        \
    }                                                                          \
    _Pragma("unroll")                                                          \
    for (int j = 0; j < 3; ++j) {                                              \
      const int g = 3 * wave + j;                                              \
      const char* src = (const char*)WT + (size_t)(8 * g + b_rsub) * 2048      \
                        + (size_t)tp * 128 + b_koff;                           \
      GLOAD_LDS16(src, buf + A_BYTES + g * 1024);                              \
    }                                                                          \
  }

#define COMPUTE(t)                                                             \
  {                                                                            \
    const char* Ab = lds + ((t) & 3) * BUF_BYTES;                              \
    const char* Bb = Ab + A_BYTES;                                             \
    _Pragma("unroll")                                                          \
    for (int ks = 0; ks < 2; ++ks) {                                           \
      bf16x8 afr[2];                                                           \
      _Pragma("unroll")                                                        \
      for (int m = 0; m < 2; ++m) {                                            \
        const int R = wm * 32 + m * 16 + l15;                                  \
        const char* rp = Ab + R * 256 + ((ks * 128 + l4 * 32) ^ aswz);         \
        f32x4 p0 = *(const f32x4*)(rp);                                        \
        f32x4 p1 = *(const f32x4*)(rp + 16);                                   \
        bf16x8 a;                                                              \
        a[0] = (bf16_t)p0.x; a[1] = (bf16_t)p0.y;                              \
        a[2] = (bf16_t)p0.z; a[3] = (bf16_t)p0.w;                              \
        a[4] = (bf16_t)p1.x; a[5] = (bf16_t)p1.y;                              \
        a[6] = (bf16_t)p1.z; a[7] = (bf16_t)p1.w;                              \
        afr[m] = a;                                                            \
      }                                                                        \
      _Pragma("unroll")                                                        \
      for (int n = 0; n < 3; ++n) {                                            \
        const int Rb = wn * 48 + n * 16 + l15;                                 \
        bf16x8 b = *(const bf16x8*)(Bb + Rb * 128 + ((ks * 64 + l4 * 16) ^ bswz)); \
        acc[0][n] = MFMA_BF16(afr[0], b, acc[0][n]);                           \
        acc[1][n] = MFMA_BF16(afr[1], b, acc[1][n]);                           \
      }                                                                        \
    }                                                                          \
  }

  // prologue: 3 steps in flight (15 outstanding); wait step 0 -> vmcnt(10)
  STAGE(0); STAGE(1); STAGE(2);
  asm volatile("s_waitcnt vmcnt(10)" ::: "memory");
  __builtin_amdgcn_s_barrier();

  for (int t = 0; t < 13; ++t) {
    COMPUTE(t);
    STAGE(t + 3);
    asm volatile("s_waitcnt vmcnt(10)" ::: "memory");  // step t+1 landed
    __builtin_amdgcn_s_barrier();
  }
  COMPUTE(13);
  asm volatile("s_waitcnt vmcnt(5)" ::: "memory");
  __builtin_amdgcn_s_barrier();
  COMPUTE(14);
  asm volatile("s_waitcnt vmcnt(0)" ::: "memory");
  __builtin_amdgcn_s_barrier();
  COMPUTE(15);
#undef STAGE
#undef COMPUTE

  // epilogue: D row = l4*4+i, col = wn*48 + n*16 + l15 (m89-verified)
  #pragma unroll
  for (int n = 0; n < 3; ++n) {
    const int col = wn * 48 + n * 16;              // wave-uniform base
    #pragma unroll
    for (int m = 0; m < 2; ++m) {
      const int r0 = rowbase + wm * 32 + m * 16 + l4 * 4;
      if (col < 64) {
        #pragma unroll
        for (int i = 0; i < 4; ++i)
          qo[(size_t)(r0 + i) * HEAD + col + l15] = (bf16_t)acc[m][n][i];
      } else if (col < 128) {
        #pragma unroll
        for (int i = 0; i < 4; ++i)
          ko[(size_t)(r0 + i) * HEAD + col - 64 + l15] = (bf16_t)acc[m][n][i];
      } else {
        const int h = col - 128 + l15;
        bf16x4 pk;
        #pragma unroll
        for (int i = 0; i < 4; ++i) pk[i] = (bf16_t)acc[m][n][i];
        *(bf16x4*)(vT + ((size_t)(r0 >> 11) * HEAD + h) * SEQ + (r0 & 2047)) = pk;
      }
    }
  }
}

// ---------------------------------------------------------------------------
// Kernel 2: attn v6 — balanced pair-block + per-block ROTATION of each
// wave's tile list (v5 had all 512 blocks starting at kv0=0 -> same-address
// L2 hotspot on K[0..64)). Rotation reorders a per-wave tile set; no-max
// softmax is order-independent.
// ---------------------------------------------------------------------------
__global__ __launch_bounds__(512, 2) void attn_kernel(
    const bf16_t* __restrict__ q, const bf16_t* __restrict__ k,
    const bf16_t* __restrict__ vT, float* __restrict__ out)
{
  __shared__ bf16_t P[8][16][72];
  __shared__ float olds[8][16][68];
  __shared__ float lsums[8][16];
  const int lane = threadIdx.x & 63;
  const int wave = threadIdx.x >> 6;
  const int l15 = lane & 15, l4 = lane >> 4;
  const int batch = blockIdx.x & 7;        // one batch per XCD cohort
  const int pair  = blockIdx.x >> 3;       // 0..63
  const int stripA = pair, stripB = 127 - pair;
  const int nA = (stripA >> 2) + 1;
  const int nB = (stripB >> 2) + 1;
  const int ntot = nA + nB;                // 33 or 34

  const bf16_t* kb = k  + (size_t)batch * SEQ * HEAD;
  const bf16_t* vb = vT + (size_t)batch * HEAD * SEQ;
  const bf16_t* qbA = q + ((size_t)batch * SEQ + stripA * 16) * HEAD;
  const bf16_t* qbB = q + ((size_t)batch * SEQ + stripB * 16) * HEAD;

  const bf16x8 aqA0 = *(const bf16x8*)(qbA + (size_t)l15 * HEAD + l4 * 8);
  const bf16x8 aqA1 = *(const bf16x8*)(qbA + (size_t)l15 * HEAD + 32 + l4 * 8);
  const bf16x8 aqB0 = *(const bf16x8*)(qbB + (size_t)l15 * HEAD + l4 * 8);
  const bf16x8 aqB1 = *(const bf16x8*)(qbB + (size_t)l15 * HEAD + 32 + l4 * 8);

  f32x4 oA[4], oB[4];
  #pragma unroll
  for (int i = 0; i < 4; ++i) {
    oA[i] = (f32x4){0.f, 0.f, 0.f, 0.f};
    oB[i] = (f32x4){0.f, 0.f, 0.f, 0.f};
  }
  float lsA[4] = {0.f, 0.f, 0.f, 0.f};
  float lsB[4] = {0.f, 0.f, 0.f, 0.f};

  // wave's tile set = {wave, wave+8, ...}; iterate rotated by block phase
  const int cw  = (ntot - wave + 7) >> 3;        // set size (4 or 5)
  const int ph  = pair;
  const int phm = ph - (ph / cw) * cw;           // ph % cw (once, pre-loop)

  for (int c = 0; c < cw; ++c) {
    int idx = c + phm; if (idx >= cw) idx -= cw;
    const int i = wave + (idx << 3);

    const bool isA = (i < nA);
    const int tile = isA ? i : (i - nA);
    const int nS   = isA ? nA : nB;
    const int qrow = (isA ? stripA : stripB) * 16;
    const int kv0  = tile * 64;
    const bf16x8 aq0 = isA ? aqA0 : aqB0;
    const bf16x8 aq1 = isA ? aqA1 : aqB1;

    // --- S = Q K^T ---
    f32x4 s[4];
    #pragma unroll
    for (int nf = 0; nf < 4; ++nf) s[nf] = (f32x4){0.f, 0.f, 0.f, 0.f};
    __builtin_amdgcn_s_setprio(1);
    #pragma unroll
    for (int nf = 0; nf < 4; ++nf) {
      const bf16_t* kp = kb + (size_t)(kv0 + nf * 16 + l15) * HEAD + l4 * 8;
      bf16x8 b0 = *(const bf16x8*)kp;
      bf16x8 b1 = *(const bf16x8*)(kp + 32);
      s[nf] = MFMA_BF16(aq0, b0, s[nf]);
      s[nf] = MFMA_BF16(aq1, b1, s[nf]);
    }
    __builtin_amdgcn_s_setprio(0);

    // --- P = exp2(S), causal mask on the diagonal tile ---
    const bool diag = (tile == nS - 1);
    float tsum[4] = {0.f, 0.f, 0.f, 0.f};
    #pragma unroll
    for (int nf = 0; nf < 4; ++nf) {
      #pragma unroll
      for (int i2 = 0; i2 < 4; ++i2) {
        float e = exp2f(s[nf][i2]);
        if (diag) {
          const int col = kv0 + nf * 16 + l15;
          const int row = qrow + l4 * 4 + i2;
          e = (col <= row) ? e : 0.f;
        }
        tsum[i2] += e;
        P[wave][l4 * 4 + i2][nf * 16 + l15] = (bf16_t)e;
      }
    }

    // V loads issued here (latency overlaps the P round-trip)
    bf16x8 v0[4], v1[4];
    #pragma unroll
    for (int nf = 0; nf < 4; ++nf) {
      const bf16_t* vp = vb + (size_t)(nf * 16 + l15) * SEQ + kv0 + l4 * 8;
      v0[nf] = *(const bf16x8*)vp;
      v1[nf] = *(const bf16x8*)(vp + 32);
    }
    asm volatile("s_waitcnt lgkmcnt(0)" ::: "memory");   // per-wave P visible

    bf16x8 ap0 = *(const bf16x8*)&P[wave][l15][l4 * 8];
    bf16x8 ap1 = *(const bf16x8*)&P[wave][l15][32 + l4 * 8];
    __builtin_amdgcn_s_setprio(1);
    if (isA) {
      #pragma unroll
      for (int nf = 0; nf < 4; ++nf) {
        oA[nf] = MFMA_BF16(ap0, v0[nf], oA[nf]);
        oA[nf] = MFMA_BF16(ap1, v1[nf], oA[nf]);
      }
      #pragma unroll
      for (int i2 = 0; i2 < 4; ++i2) lsA[i2] += tsum[i2];
    } else {
      #pragma unroll
      for (int nf = 0; nf < 4; ++nf) {
        oB[nf] = MFMA_BF16(ap0, v0[nf], oB[nf]);
        oB[nf] = MFMA_BF16(ap1, v1[nf], oB[nf]);
      }
      #pragma unroll
      for (int i2 = 0; i2 < 4; ++i2) lsB[i2] += tsum[i2];
    }
    __builtin_amdgcn_s_setprio(0);
  }

  // ---- two-pass reduce (same LDS reused; barrier-separated) ----
  #pragma unroll
  for (int pass = 0; pass < 2; ++pass) {
    #pragma unroll
    for (int i = 0; i < 4; ++i) {
      float v = pass == 0 ? lsA[i] : lsB[i];
      v += __shfl_xor(v, 1);
      v += __shfl_xor(v, 2);
      v += __shfl_xor(v, 4);
      v += __shfl_xor(v, 8);
      if (l15 == 0) lsums[wave][l4 * 4 + i] = v;
    }
    #pragma unroll
    for (int nf = 0; nf < 4; ++nf)
      #pragma unroll
      for (int i = 0; i < 4; ++i)
        olds[wave][l4 * 4 + i][nf * 16 + l15] = pass == 0 ? oA[nf][i] : oB[nf][i];
    __syncthreads();

    if (threadIdx.x < 256) {
      const int r = threadIdx.x >> 4, c0 = threadIdx.x & 15;
      float sum = 0.f;
      #pragma unroll
      for (int w = 0; w < 8; ++w) sum += lsums[w][r];
      const float rinv = 1.0f / sum;
      const int strip = pass == 0 ? stripA : stripB;
      float* ob = out + ((size_t)batch * SEQ + strip * 16 + r) * HEAD;
      #pragma unroll
      for (int j = 0; j < 4; ++j) {
        const int c = c0 + 16 * j;
        float v = 0.f;
        #pragma unroll
        for (int w = 0; w < 8; ++w) v += olds[w][r][c];
        ob[c] = v * rinv;
      }
    }
    __syncthreads();
  }
}

// ---------------------------------------------------------------------------
extern "C" void kernel_launch(void* const* d_in, const int* in_sizes, int n_in,
                              void* d_out, int out_size, void* d_ws, size_t ws_size,
                              hipStream_t stream)
{
  const float* x  = (const float*)d_in[0];
  const float* Wq = (const float*)d_in[1];
  const float* Wk = (const float*)d_in[2];
  const float* Wv = (const float*)d_in[3];
  float* out = (float*)d_out;

  const size_t SZ_QKV = (size_t)BATCH * SEQ * HEAD * sizeof(bf16_t);   // 2 MiB
  if (ws_size < 3 * SZ_QKV + (size_t)192 * EMB * sizeof(bf16_t)) return;
  char* ws = (char*)d_ws;
  bf16_t* qo = (bf16_t*)(ws);
  bf16_t* ko = (bf16_t*)(ws + SZ_QKV);
  bf16_t* vT = (bf16_t*)(ws + 2 * SZ_QKV);
  bf16_t* WT = (bf16_t*)(ws + 3 * SZ_QKV);

  wtrans_kernel<<<dim3(48),  dim3(256), 0, stream>>>(Wq, Wk, Wv, WT);
  qkv_kernel  <<<dim3(256), dim3(512), 0, stream>>>(x, WT, qo, ko, vT);
  attn_kernel <<<dim3(512), dim3(512), 0, stream>>>(qo, ko, vT, out);
}

// Round 10
// 56.571 us; speedup vs baseline: 1.1483x; 1.0539x over previous
//
#include <hip/hip_runtime.h>
#include <hip/hip_bf16.h>

typedef __bf16 bf16_t;
typedef __bf16 bf16x8 __attribute__((ext_vector_type(8)));
typedef __bf16 bf16x4 __attribute__((ext_vector_type(4)));
typedef float  f32x4  __attribute__((ext_vector_type(4)));

#define MFMA_BF16(A, B, C) __builtin_amdgcn_mfma_f32_16x16x32_bf16((A), (B), (C), 0, 0, 0)

#define BATCH 8
#define SEQ   2048
#define EMB   1024
#define HEAD  64

typedef __attribute__((address_space(3))) void as3_void;
typedef const __attribute__((address_space(1))) void as1_void;
#define GLOAD_LDS16(g, l) \
  __builtin_amdgcn_global_load_lds((as1_void*)(g), (as3_void*)(l), 16, 0, 0)

// ---------------------------------------------------------------------------
// Kernel 0: W [1024][64] fp32 x3 -> WT bf16 [192][1024] (transposed).
// Wq gets scale log2(e)/32 folded in (attn uses exp2).
// ---------------------------------------------------------------------------
__global__ __launch_bounds__(256) void wtrans_kernel(
    const float* __restrict__ Wq, const float* __restrict__ Wk,
    const float* __restrict__ Wv, bf16_t* __restrict__ WT)
{
  __shared__ float tile[64][65];
  const int m  = blockIdx.x >> 4;
  const int kt = blockIdx.x & 15;
  const float* W = (m == 0) ? Wq : (m == 1) ? Wk : Wv;
  const float scale = (m == 0) ? 0.045084219f : 1.0f;   // log2(e)/32
  const int k0 = kt * 64;

  #pragma unroll
  for (int i = 0; i < 16; ++i) {
    int idx = i * 256 + threadIdx.x;
    int kk = idx >> 6, n = idx & 63;
    tile[kk][n] = W[(size_t)(k0 + kk) * HEAD + n];
  }
  __syncthreads();
  #pragma unroll
  for (int i = 0; i < 16; ++i) {
    int idx = i * 256 + threadIdx.x;
    int n = idx >> 6, kk = idx & 63;
    WT[((size_t)m * HEAD + n) * EMB + k0 + kk] = (bf16_t)(tile[kk][n] * scale);
  }
}

// ---------------------------------------------------------------------------
// Kernel 1: qkv v9 (UNCHANGED from R8 — measured ~18 µs).
// BM=64 x N=192 x BK=64, 256 blocks (1/CU), 8 waves (2m x 4n), full K.
// Ring-4 x 40KB (160KB LDS), counted vmcnt(10), raw s_barrier; A/B both
// XOR-swizzled via pre-swizzled glds source (rule #21); k-phase stagger.
// ---------------------------------------------------------------------------
#define A_BYTES 16384     // 64 rows x 256 B (fp32, BK=64)
#define B_BYTES 24576     // 192 rows x 128 B (bf16, BK=64)
#define BUF_BYTES 40960

__global__ __launch_bounds__(512, 1) void qkv_kernel(
    const float* __restrict__ x, const bf16_t* __restrict__ WT,
    bf16_t* __restrict__ qo, bf16_t* __restrict__ ko, bf16_t* __restrict__ vT)
{
  __shared__ char lds[4 * BUF_BYTES];            // 160 KB

  const int tid  = threadIdx.x;
  const int lane = tid & 63;
  const int wave = tid >> 6;                     // 0..7
  const int l15 = lane & 15, l4 = lane >> 4;
  const int wm = wave >> 2, wn = wave & 3;
  const int rowbase = blockIdx.x * 64;
  const int phase = (blockIdx.x >> 3) & 15;      // k-stagger (sum order-free)

  const int a_rsub = lane >> 4;
  const int b_rsub = lane >> 3;
  const int b_koff = ((lane & 7) * 16) ^ (b_rsub << 4);

  const int aswz = (l15 & 7) << 5;               // read-side XORs (row&7==l15&7)
  const int bswz = (l15 & 7) << 4;

  f32x4 acc[2][3];
  #pragma unroll
  for (int m = 0; m < 2; ++m)
    #pragma unroll
    for (int n = 0; n < 3; ++n) acc[m][n] = (f32x4){0.f, 0.f, 0.f, 0.f};

#define STAGE(t)                                                               \
  {                                                                            \
    char* buf = lds + ((t) & 3) * BUF_BYTES;                                   \
    const int tp = ((t) + phase) & 15;                                         \
    _Pragma("unroll")                                                          \
    for (int j = 0; j < 2; ++j) {                                              \
      const int g = 2 * wave + j;                                              \
      const int koff = (l15 * 16) ^ ((((j) << 2) | a_rsub) << 5);              \
      const char* src = (const char*)x + (size_t)(rowbase + 4 * g + a_rsub)    \
                        * 4096 + (size_t)tp * 256 + koff;                      \
      GLOAD_LDS16(src, buf + g * 1024);                                        \
    }                                                                          \
    _Pragma("unroll")                                                          \
    for (int j = 0; j < 3; ++j) {                                              \
      const int g = 3 * wave + j;                                              \
      const char* src = (const char*)WT + (size_t)(8 * g + b_rsub) * 2048      \
                        + (size_t)tp * 128 + b_koff;                           \
      GLOAD_LDS16(src, buf + A_BYTES + g * 1024);                              \
    }                                                                          \
  }

#define COMPUTE(t)                                                             \
  {                                                                            \
    const char* Ab = lds + ((t) & 3) * BUF_BYTES;                              \
    const char* Bb = Ab + A_BYTES;                                             \
    _Pragma("unroll")                                                          \
    for (int ks = 0; ks < 2; ++ks) {                                           \
      bf16x8 afr[2];                                                           \
      _Pragma("unroll")                                                        \
      for (int m = 0; m < 2; ++m) {                                            \
        const int R = wm * 32 + m * 16 + l15;                                  \
        const char* rp = Ab + R * 256 + ((ks * 128 + l4 * 32) ^ aswz);         \
        f32x4 p0 = *(const f32x4*)(rp);                                        \
        f32x4 p1 = *(const f32x4*)(rp + 16);                                   \
        bf16x8 a;                                                              \
        a[0] = (bf16_t)p0.x; a[1] = (bf16_t)p0.y;                              \
        a[2] = (bf16_t)p0.z; a[3] = (bf16_t)p0.w;                              \
        a[4] = (bf16_t)p1.x; a[5] = (bf16_t)p1.y;                              \
        a[6] = (bf16_t)p1.z; a[7] = (bf16_t)p1.w;                              \
        afr[m] = a;                                                            \
      }                                                                        \
      _Pragma("unroll")                                                        \
      for (int n = 0; n < 3; ++n) {                                            \
        const int Rb = wn * 48 + n * 16 + l15;                                 \
        bf16x8 b = *(const bf16x8*)(Bb + Rb * 128 + ((ks * 64 + l4 * 16) ^ bswz)); \
        acc[0][n] = MFMA_BF16(afr[0], b, acc[0][n]);                           \
        acc[1][n] = MFMA_BF16(afr[1], b, acc[1][n]);                           \
      }                                                                        \
    }                                                                          \
  }

  STAGE(0); STAGE(1); STAGE(2);
  asm volatile("s_waitcnt vmcnt(10)" ::: "memory");
  __builtin_amdgcn_s_barrier();

  for (int t = 0; t < 13; ++t) {
    COMPUTE(t);
    STAGE(t + 3);
    asm volatile("s_waitcnt vmcnt(10)" ::: "memory");
    __builtin_amdgcn_s_barrier();
  }
  COMPUTE(13);
  asm volatile("s_waitcnt vmcnt(5)" ::: "memory");
  __builtin_amdgcn_s_barrier();
  COMPUTE(14);
  asm volatile("s_waitcnt vmcnt(0)" ::: "memory");
  __builtin_amdgcn_s_barrier();
  COMPUTE(15);
#undef STAGE
#undef COMPUTE

  #pragma unroll
  for (int n = 0; n < 3; ++n) {
    const int col = wn * 48 + n * 16;
    #pragma unroll
    for (int m = 0; m < 2; ++m) {
      const int r0 = rowbase + wm * 32 + m * 16 + l4 * 4;
      if (col < 64) {
        #pragma unroll
        for (int i = 0; i < 4; ++i)
          qo[(size_t)(r0 + i) * HEAD + col + l15] = (bf16_t)acc[m][n][i];
      } else if (col < 128) {
        #pragma unroll
        for (int i = 0; i < 4; ++i)
          ko[(size_t)(r0 + i) * HEAD + col - 64 + l15] = (bf16_t)acc[m][n][i];
      } else {
        const int h = col - 128 + l15;
        bf16x4 pk;
        #pragma unroll
        for (int i = 0; i < 4; ++i) pk[i] = (bf16_t)acc[m][n][i];
        *(bf16x4*)(vT + ((size_t)(r0 >> 11) * HEAD + h) * SEQ + (r0 & 2047)) = pk;
      }
    }
  }
}

// ---------------------------------------------------------------------------
// Kernel 2: attn v7 — rotation REVERTED (v6's per-block rotation destroyed
// co-timed L2 reuse: 21 -> 39 µs) + register de-pressure:
//  * wave owns ONE strip (waves 0-3 K-split strip A, 4-7 strip B) ->
//    single o[4]/lsum[4]/aq pair (~80 live regs, was ~110 dual-acc).
//  * launch_bounds(512,1): VGPR cap 512 (v6 got squeezed to 64 -> spills).
//  * LDS trimmed to 52.2 KB (olds pitch 65) -> 3 blocks/CU = 24 waves/CU.
// ---------------------------------------------------------------------------
__global__ __launch_bounds__(512, 1) void attn_kernel(
    const bf16_t* __restrict__ q, const bf16_t* __restrict__ k,
    const bf16_t* __restrict__ vT, float* __restrict__ out)
{
  __shared__ bf16_t P[8][16][72];      // 18.4 KB
  __shared__ float olds[8][16][65];    // 33.3 KB
  __shared__ float lsums[8][16];       // 0.5 KB
  const int lane = threadIdx.x & 63;
  const int wave = threadIdx.x >> 6;
  const int l15 = lane & 15, l4 = lane >> 4;
  const int batch = blockIdx.x & 7;        // one batch per XCD cohort
  const int pair  = blockIdx.x >> 3;       // 0..63; pair 0 has deepest B strip
  const int side  = wave >> 2;             // 0 = strip A, 1 = strip B
  const int wsub  = wave & 3;
  const int strip = side ? (127 - pair) : pair;
  const int qrow  = strip * 16;
  const int ntiles = (qrow >> 6) + 1;

  const bf16_t* kb = k  + (size_t)batch * SEQ * HEAD;
  const bf16_t* vb = vT + (size_t)batch * HEAD * SEQ;
  const bf16_t* qb = q  + ((size_t)batch * SEQ + qrow) * HEAD;

  const bf16x8 aq0 = *(const bf16x8*)(qb + (size_t)l15 * HEAD + l4 * 8);
  const bf16x8 aq1 = *(const bf16x8*)(qb + (size_t)l15 * HEAD + 32 + l4 * 8);

  f32x4 o[4];
  #pragma unroll
  for (int i = 0; i < 4; ++i) o[i] = (f32x4){0.f, 0.f, 0.f, 0.f};
  float lsum[4] = {0.f, 0.f, 0.f, 0.f};

  for (int t = wsub; t < ntiles; t += 4) {
    const int kv0 = t * 64;

    // --- S = Q K^T (K direct from L2) ---
    f32x4 s[4];
    #pragma unroll
    for (int nf = 0; nf < 4; ++nf) s[nf] = (f32x4){0.f, 0.f, 0.f, 0.f};
    __builtin_amdgcn_s_setprio(1);
    #pragma unroll
    for (int nf = 0; nf < 4; ++nf) {
      const bf16_t* kp = kb + (size_t)(kv0 + nf * 16 + l15) * HEAD + l4 * 8;
      bf16x8 b0 = *(const bf16x8*)kp;
      bf16x8 b1 = *(const bf16x8*)(kp + 32);
      s[nf] = MFMA_BF16(aq0, b0, s[nf]);
      s[nf] = MFMA_BF16(aq1, b1, s[nf]);
    }
    __builtin_amdgcn_s_setprio(0);

    // --- P = exp2(S) (log2e folded into Wq), causal mask on diag tile ---
    const bool diag = (t == ntiles - 1);
    #pragma unroll
    for (int nf = 0; nf < 4; ++nf) {
      #pragma unroll
      for (int i2 = 0; i2 < 4; ++i2) {
        float e = exp2f(s[nf][i2]);
        if (diag) {
          const int col = kv0 + nf * 16 + l15;
          const int row = qrow + l4 * 4 + i2;
          e = (col <= row) ? e : 0.f;
        }
        lsum[i2] += e;
        P[wave][l4 * 4 + i2][nf * 16 + l15] = (bf16_t)e;
      }
    }

    // V loads issued here (latency overlaps the P LDS round-trip)
    bf16x8 v0[4], v1[4];
    #pragma unroll
    for (int nf = 0; nf < 4; ++nf) {
      const bf16_t* vp = vb + (size_t)(nf * 16 + l15) * SEQ + kv0 + l4 * 8;
      v0[nf] = *(const bf16x8*)vp;
      v1[nf] = *(const bf16x8*)(vp + 32);
    }
    asm volatile("s_waitcnt lgkmcnt(0)" ::: "memory");   // per-wave P visible

    bf16x8 ap0 = *(const bf16x8*)&P[wave][l15][l4 * 8];
    bf16x8 ap1 = *(const bf16x8*)&P[wave][l15][32 + l4 * 8];
    __builtin_amdgcn_s_setprio(1);
    #pragma unroll
    for (int nf = 0; nf < 4; ++nf) {
      o[nf] = MFMA_BF16(ap0, v0[nf], o[nf]);
      o[nf] = MFMA_BF16(ap1, v1[nf], o[nf]);
    }
    __builtin_amdgcn_s_setprio(0);
  }

  // ---- per-wave partials -> LDS ----
  #pragma unroll
  for (int i = 0; i < 4; ++i) {
    float v = lsum[i];
    v += __shfl_xor(v, 1);
    v += __shfl_xor(v, 2);
    v += __shfl_xor(v, 4);
    v += __shfl_xor(v, 8);
    if (l15 == 0) lsums[wave][l4 * 4 + i] = v;
  }
  #pragma unroll
  for (int nf = 0; nf < 4; ++nf)
    #pragma unroll
    for (int i = 0; i < 4; ++i)
      olds[wave][l4 * 4 + i][nf * 16 + l15] = o[nf][i];
  __syncthreads();

  // ---- cross-wave reduce: threads 0-255 -> strip A, 256-511 -> strip B ----
  {
    const int g  = threadIdx.x >> 8;
    const int tt = threadIdx.x & 255;
    const int r = tt >> 4, c0 = tt & 15;
    const int sstrip = g ? (127 - pair) : pair;
    const int w0 = g * 4;
    const float s = lsums[w0][r] + lsums[w0+1][r] + lsums[w0+2][r] + lsums[w0+3][r];
    const float rinv = 1.0f / s;
    float* ob = out + ((size_t)batch * SEQ + sstrip * 16 + r) * HEAD;
    #pragma unroll
    for (int j = 0; j < 4; ++j) {
      const int c = c0 + 16 * j;
      float v = olds[w0][r][c] + olds[w0+1][r][c] + olds[w0+2][r][c] + olds[w0+3][r][c];
      ob[c] = v * rinv;
    }
  }
}

// ---------------------------------------------------------------------------
extern "C" void kernel_launch(void* const* d_in, const int* in_sizes, int n_in,
                              void* d_out, int out_size, void* d_ws, size_t ws_size,
                              hipStream_t stream)
{
  const float* x  = (const float*)d_in[0];
  const float* Wq = (const float*)d_in[1];
  const float* Wk = (const float*)d_in[2];
  const float* Wv = (const float*)d_in[3];
  float* out = (float*)d_out;

  const size_t SZ_QKV = (size_t)BATCH * SEQ * HEAD * sizeof(bf16_t);   // 2 MiB
  if (ws_size < 3 * SZ_QKV + (size_t)192 * EMB * sizeof(bf16_t)) return;
  char* ws = (char*)d_ws;
  bf16_t* qo = (bf16_t*)(ws);
  bf16_t* ko = (bf16_t*)(ws + SZ_QKV);
  bf16_t* vT = (bf16_t*)(ws + 2 * SZ_QKV);
  bf16_t* WT = (bf16_t*)(ws + 3 * SZ_QKV);

  wtrans_kernel<<<dim3(48),  dim3(256), 0, stream>>>(Wq, Wk, Wv, WT);
  qkv_kernel  <<<dim3(256), dim3(512), 0, stream>>>(x, WT, qo, ko, vT);
  attn_kernel <<<dim3(512), dim3(512), 0, stream>>>(qo, ko, vT, out);
}